// Round 5
// baseline (379.359 us; speedup 1.0000x reference)
//
#include <hip/hip_runtime.h>
#include <hip/hip_bf16.h>
#include <cstdint>
#include <cstddef>

// ---------------------------------------------------------------------------
// SelfAttention via pre-contracted weights (full-dim attention, no head split):
//   W~T = Wk^T Wq ; Wc = Wo Wv        (1024^2, computed on 128^2-tile core)
//   Qx  = X @ W~  ; Vc = X @ Wc^T     (fused one pass, V stored transposed)
//   P'  = exp(Qx @ X^T * 0.125) ; l = rowsum(P')
//   y   = (P' @ Vc)/l + b             (PV epilogue writes final f32 out)
// R9: dispatch-count reduction 8 -> 5. All casts + transpose-cast + L-zeroing
// merged into ONE `prep` kernel (block-range branches). GEMM cores unchanged
// from R8 (gap-measurement probe: per-kernel counters should not move).
// ---------------------------------------------------------------------------

typedef __bf16 bf16x8 __attribute__((ext_vector_type(8)));
typedef float f32x4 __attribute__((ext_vector_type(4)));

__device__ __forceinline__ void gl_lds16(const void* g, void* l) {
  __builtin_amdgcn_global_load_lds((const __attribute__((address_space(1))) void*)g,
                                   (__attribute__((address_space(3))) void*)l, 16, 0, 0);
}

__device__ __forceinline__ void cast8(const float* __restrict__ in,
                                      __hip_bfloat16* __restrict__ out, int i) {
  float4 a = *(const float4*)(in + i);
  float4 b = *(const float4*)(in + i + 4);
  __align__(16) __hip_bfloat16 o[8];
  o[0] = __float2bfloat16(a.x); o[1] = __float2bfloat16(a.y);
  o[2] = __float2bfloat16(a.z); o[3] = __float2bfloat16(a.w);
  o[4] = __float2bfloat16(b.x); o[5] = __float2bfloat16(b.y);
  o[6] = __float2bfloat16(b.z); o[7] = __float2bfloat16(b.w);
  *(uint4*)(out + i) = *(const uint4*)o;
}

// ---------------- prep: all casts + w_qkv transpose-cast + zero L -----------
// segments by blockIdx.x: [0,8192) cast x->Xb ; [8192,8704) cast w_out->Wob ;
// [8704,9472) tcast w_qkv (z=0 Wq->slot2, z=1 Wk->slot0, z=2 Wv->slot3) ;
// [9472,9488) zero L (16384 floats).
__global__ __launch_bounds__(256) void prep(
    const float* __restrict__ x, const float* __restrict__ w_qkv,
    const float* __restrict__ w_out,
    __hip_bfloat16* __restrict__ Xb, __hip_bfloat16* __restrict__ wsb,
    __hip_bfloat16* __restrict__ Wob, float* __restrict__ L) {
  __shared__ float t[64][65];
  const int bx = blockIdx.x;
  const int tid = threadIdx.x;
  if (bx < 8192) {
    cast8(x, Xb, (bx * 256 + tid) * 8);
  } else if (bx < 8704) {
    cast8(w_out, Wob, ((bx - 8192) * 256 + tid) * 8);
  } else if (bx < 9472) {
    const int t3 = bx - 8704;
    const int z = t3 >> 8;
    const int rem = t3 & 255;
    const int by = rem >> 4, bxx = rem & 15;
    const int zo = (z == 0) ? 2 : ((z == 1) ? 0 : 3);
    const float* src = w_qkv + (size_t)z * 1024 * 1024;
    __hip_bfloat16* dst = wsb + (size_t)zo * 1024 * 1024;
    const int r0 = by * 64, c0 = bxx * 64;
    const int lr = tid >> 2, lc4 = tid & 3;
    #pragma unroll
    for (int j = 0; j < 4; ++j) {
      float4 v = *(const float4*)(src + (size_t)(r0 + lr) * 1024 + c0 + lc4 * 16 + j * 4);
      t[lr][lc4 * 16 + j * 4 + 0] = v.x;
      t[lr][lc4 * 16 + j * 4 + 1] = v.y;
      t[lr][lc4 * 16 + j * 4 + 2] = v.z;
      t[lr][lc4 * 16 + j * 4 + 3] = v.w;
    }
    __syncthreads();
    const int oc = tid >> 2;
    #pragma unroll
    for (int s2 = 0; s2 < 2; ++s2) {
      const int s = (tid & 3) + s2 * 4;
      __align__(16) __hip_bfloat16 o[8];
      #pragma unroll
      for (int j = 0; j < 8; ++j) o[j] = __float2bfloat16(t[s * 8 + j][oc]);
      *(uint4*)(dst + (size_t)(c0 + oc) * 1024 + r0 + s * 8) = *(const uint4*)o;
    }
  } else {
    const f32x4 z4 = {0.f, 0.f, 0.f, 0.f};
    *(f32x4*)(L + ((bx - 9472) * 256 + tid) * 4) = z4;
  }
}

// ============ small GEMM core: 128x128 tile, BK=64 (proven R4 core) ========
#define GEMM_CORE64(APTR, LDA, BPTR, LDB, KLEN)                                    \
  __shared__ __align__(16) __hip_bfloat16 As[128 * 64];                            \
  __shared__ __align__(16) __hip_bfloat16 Bs[128 * 64];                            \
  const int tid  = threadIdx.x;                                                    \
  const int lane = tid & 63;                                                       \
  const int q    = lane >> 4;                                                      \
  const int m16  = lane & 15;                                                      \
  const int wave = tid >> 6;                                                       \
  const int wr   = wave >> 1;                                                      \
  const int wc   = wave & 1;                                                       \
  const int row0 = blockIdx.y * 128;                                               \
  const int col0 = blockIdx.x * 128;                                               \
  unsigned offA[4], offB[4];                                                       \
  _Pragma("unroll") for (int i = 0; i < 4; ++i) {                                  \
    const int c = tid + 256 * i;                                                   \
    const int r = c >> 3, kc = ((c ^ (c >> 3)) & 7) * 8;                           \
    offA[i] = (unsigned)(row0 + r) * (unsigned)(LDA) + kc;                         \
    offB[i] = (unsigned)(col0 + r) * (unsigned)(LDB) + kc;                         \
  }                                                                                \
  const f32x4 zeroS = {0.f, 0.f, 0.f, 0.f};                                        \
  f32x4 acc[4][4];                                                                 \
  _Pragma("unroll") for (int i = 0; i < 4; ++i)                                    \
    _Pragma("unroll") for (int j = 0; j < 4; ++j) acc[i][j] = zeroS;               \
  const int sl0 = (q ^ (m16 & 7)) * 8;                                             \
  for (int k0 = 0; k0 < (KLEN); k0 += 64) {                                        \
    _Pragma("unroll") for (int i = 0; i < 4; ++i) {                                \
      gl_lds16((APTR) + offA[i] + k0, As + ((size_t)tid + 256 * i) * 8);           \
      gl_lds16((BPTR) + offB[i] + k0, Bs + ((size_t)tid + 256 * i) * 8);           \
    }                                                                              \
    __syncthreads();                                                               \
    _Pragma("unroll") for (int step = 0; step < 2; ++step) {                       \
      const int so = sl0 ^ (step * 32);                                            \
      bf16x8 af[4], bfr[4];                                                        \
      _Pragma("unroll") for (int mi = 0; mi < 4; ++mi)                             \
        af[mi] = *(const bf16x8*)(As + (wr * 64 + mi * 16 + m16) * 64 + so);       \
      _Pragma("unroll") for (int ni = 0; ni < 4; ++ni)                             \
        bfr[ni] = *(const bf16x8*)(Bs + (wc * 64 + ni * 16 + m16) * 64 + so);      \
      _Pragma("unroll") for (int mi = 0; mi < 4; ++mi)                             \
        _Pragma("unroll") for (int ni = 0; ni < 4; ++ni)                           \
          acc[mi][ni] = __builtin_amdgcn_mfma_f32_16x16x32_bf16(af[mi], bfr[ni],   \
                                                                acc[mi][ni],0,0,0);\
    }                                                                              \
    __syncthreads();                                                               \
  }                                                                                \
  const int crow = row0 + wr * 64 + q * 4;                                         \
  const int ccol = col0 + wc * 64 + m16;

// batched small gemm, bf16 out: C = A @ B^T
__global__ __launch_bounds__(256) void gemm_small(
    const __hip_bfloat16* __restrict__ A, int lda, long long sA,
    const __hip_bfloat16* __restrict__ B, int ldb, long long sB,
    __hip_bfloat16* __restrict__ Cv, int ldc, long long sC, int K)
{
  const int bz = blockIdx.z;
  GEMM_CORE64(A + (size_t)bz * sA, lda, B + (size_t)bz * sB, ldb, K)
  __hip_bfloat16* C = Cv + (size_t)bz * sC;
  #pragma unroll
  for (int mi = 0; mi < 4; ++mi)
    #pragma unroll
    for (int ni = 0; ni < 4; ++ni)
      #pragma unroll
      for (int r = 0; r < 4; ++r)
        C[(size_t)(crow + mi * 16 + r) * ldc + ccol + ni * 16] = __float2bfloat16(acc[mi][ni][r]);
}

// ============ big GEMM core: 256x256 tile, BK=64, single-barrier phases ====
// (R7 core, unchanged: planes [256][32], source-side XOR swizzle, gload_lds
//  width 16, counted vmcnt(8), one barrier per phase, peeled 2-tile tail.)
#define ST1(SRCP, OFFS, LDSBASE, TT, KS)                                           \
  { const int kb_ = (TT) * 64 + (KS) * 32;                                         \
    _Pragma("unroll") for (int i = 0; i < 2; ++i)                                  \
      gl_lds16((SRCP) + OFFS[i] + kb_,                                             \
               sm + (LDSBASE) + (size_t)(tid + 512 * i) * 8); }

#define LDAF(APL, CH)                                                              \
  _Pragma("unroll") for (int mi = 0; mi < 4; ++mi)                                 \
    af[mi] = *(const bf16x8*)(sm + (APL) * 8192 + arow + ((CH) * 4 + mi) * 512);
#define LDBF(BPL)                                                                  \
  _Pragma("unroll") for (int ni = 0; ni < 4; ++ni)                                 \
    bfr[ni] = *(const bf16x8*)(sm + 32768 + (BPL) * 8192 + brow + ni * 512);

#define MF16(CH)                                                                   \
  __builtin_amdgcn_s_setprio(1);                                                   \
  _Pragma("unroll") for (int mi = 0; mi < 4; ++mi)                                 \
    _Pragma("unroll") for (int ni = 0; ni < 4; ++ni)                               \
      acc[(CH) * 4 + mi][ni] = __builtin_amdgcn_mfma_f32_16x16x32_bf16(            \
          af[mi], bfr[ni], acc[(CH) * 4 + mi][ni], 0, 0, 0);                       \
  __builtin_amdgcn_s_setprio(0);

#define ENDP(VMN)                                                                  \
  asm volatile("s_waitcnt vmcnt(" #VMN ")" ::: "memory");                          \
  __builtin_amdgcn_s_barrier();                                                    \
  __builtin_amdgcn_sched_barrier(0);
#define ENDB()                                                                     \
  __builtin_amdgcn_s_barrier();                                                    \
  __builtin_amdgcn_sched_barrier(0);

#define GEMM_CORE256(APTR, LDA, BPTR, LDB, KLEN)                                   \
  __shared__ __align__(16) __hip_bfloat16 sm[65536]; /* 128 KiB */                 \
  const __hip_bfloat16* Abase_ = (APTR);                                           \
  const __hip_bfloat16* Bbase_ = (BPTR);                                           \
  const int tid  = threadIdx.x;                                                    \
  const int lane = tid & 63;                                                       \
  const int q    = lane >> 4;                                                      \
  const int m16  = lane & 15;                                                      \
  const int wave = tid >> 6;                                                       \
  const int wr   = wave >> 2;                                                      \
  const int wc   = wave & 3;                                                       \
  const int row0 = blockIdx.y * 256;                                               \
  const int col0 = blockIdx.x * 256;                                               \
  unsigned srcA[2], srcB[2];                                                       \
  _Pragma("unroll") for (int i = 0; i < 2; ++i) {                                  \
    const int c_ = tid + 512 * i;                                                  \
    const int r_ = c_ >> 2;                                                        \
    const int kc_ = ((c_ & 3) ^ ((r_ >> 1) & 3)) * 8;                              \
    srcA[i] = (unsigned)(row0 + r_) * (unsigned)(LDA) + (unsigned)kc_;             \
    srcB[i] = (unsigned)(col0 + r_) * (unsigned)(LDB) + (unsigned)kc_;             \
  }                                                                                \
  const int NT = (KLEN) >> 6;                                                      \
  f32x4 acc[8][4];                                                                 \
  { const f32x4 z_ = {0.f, 0.f, 0.f, 0.f};                                         \
    _Pragma("unroll") for (int i = 0; i < 8; ++i)                                  \
      _Pragma("unroll") for (int j = 0; j < 4; ++j) acc[i][j] = z_; }              \
  const int soff = (q ^ ((m16 >> 1) & 3)) * 8;                                     \
  const int arow = (wr * 128 + m16) * 32 + soff;                                   \
  const int brow = (wc * 64 + m16) * 32 + soff;                                    \
  bf16x8 af[4], bfr[4];                                                            \
  ST1(Abase_, srcA, 0,             0, 0)                                           \
  ST1(Bbase_, srcB, 32768,         0, 0)                                           \
  ST1(Abase_, srcA, 8192,          0, 1)                                           \
  ST1(Bbase_, srcB, 32768 + 8192,  0, 1)                                           \
  ST1(Abase_, srcA, 16384,         1, 0)                                           \
  ST1(Bbase_, srcB, 32768 + 16384, 1, 0)                                           \
  ENDP(8)                                                                          \
  for (int t = 0; t < NT - 2; t += 2) {                                            \
    LDAF(0,0) LDBF(0) ST1(Abase_, srcA, 24576,         t+1, 1) MF16(0) ENDP(8)     \
    LDAF(0,1)         ST1(Bbase_, srcB, 32768 + 24576, t+1, 1) MF16(1) ENDP(8)     \
    LDAF(1,0) LDBF(1) ST1(Abase_, srcA, 0,             t+2, 0) MF16(0) ENDP(8)     \
    LDAF(1,1)         ST1(Bbase_, srcB, 32768,         t+2, 0) MF16(1) ENDP(8)     \
    LDAF(2,0) LDBF(2) ST1(Abase_, srcA, 8192,          t+2, 1) MF16(0) ENDP(8)     \
    LDAF(2,1)         ST1(Bbase_, srcB, 32768 + 8192,  t+2, 1) MF16(1) ENDP(8)     \
    LDAF(3,0) LDBF(3) ST1(Abase_, srcA, 16384,         t+3, 0) MF16(0) ENDP(8)     \
    LDAF(3,1)         ST1(Bbase_, srcB, 32768 + 16384, t+3, 0) MF16(1) ENDP(8)     \
  }                                                                                \
  LDAF(0,0) LDBF(0) ST1(Abase_, srcA, 24576,         NT-1, 1) MF16(0) ENDP(8)      \
  LDAF(0,1)         ST1(Bbase_, srcB, 32768 + 24576, NT-1, 1) MF16(1) ENDP(8)      \
  LDAF(1,0) LDBF(1)                                           MF16(0) ENDP(6)      \
  LDAF(1,1)                                                   MF16(1) ENDP(4)      \
  LDAF(2,0) LDBF(2)                                           MF16(0) ENDP(2)      \
  LDAF(2,1)                                                   MF16(1) ENDP(0)      \
  LDAF(3,0) LDBF(3)                                           MF16(0) ENDB()       \
  LDAF(3,1)                                                   MF16(1)              \
  const int crow = row0 + wr * 128 + q * 4;                                        \
  const int ccol = col0 + wc * 64 + m16;

// ---------------- Qx/Vc fused projection ----------------
// B = [W~T ; Wc] (2048 rows). blockIdx.x<4 -> Qx[m,0..1023] bf16;
// x>=4 -> Vt[(col-1024), m] transposed bf16.
__global__ __launch_bounds__(512) void gemm_qv(
    const __hip_bfloat16* __restrict__ A, int lda,
    const __hip_bfloat16* __restrict__ B, int ldb,
    __hip_bfloat16* __restrict__ Qx,
    __hip_bfloat16* __restrict__ Vt, int M, int K)
{
  GEMM_CORE256(A, lda, B, ldb, K)
  if (blockIdx.x < 4) {
    #pragma unroll
    for (int mi = 0; mi < 8; ++mi)
      #pragma unroll
      for (int ni = 0; ni < 4; ++ni)
        #pragma unroll
        for (int r = 0; r < 4; ++r)
          Qx[(size_t)(crow + mi * 16 + r) * 1024 + ccol + ni * 16] = __float2bfloat16(acc[mi][ni][r]);
  } else {
    #pragma unroll
    for (int mi = 0; mi < 8; ++mi) {
      const int rowbase = crow + mi * 16;  // multiple of 4 -> 8B-aligned dest
      #pragma unroll
      for (int ni = 0; ni < 4; ++ni) {
        const int vc = ccol + ni * 16 - 1024;
        __align__(8) __hip_bfloat16 o[4];
        #pragma unroll
        for (int r = 0; r < 4; ++r) o[r] = __float2bfloat16(acc[mi][ni][r]);
        *(uint2*)(Vt + (size_t)vc * M + rowbase) = *(const uint2*)o;
      }
    }
  }
}

// ---------------- QK^T gemm, fused exp epilogue + atomic row sums ----------
__global__ __launch_bounds__(512) void gemm_qk_exp(
    const __hip_bfloat16* __restrict__ A, int lda, long long sA,
    const __hip_bfloat16* __restrict__ B, int ldb, long long sB,
    __hip_bfloat16* __restrict__ Pv, int ldc, long long sC,
    float* __restrict__ Lsum, int ldl, int K)
{
  const int bz = blockIdx.z;
  GEMM_CORE256(A + (size_t)bz * sA, lda, B + (size_t)bz * sB, ldb, K)
  __hip_bfloat16* C = Pv + (size_t)bz * sC;
  float* Lrow = Lsum + (size_t)bz * ldl;
  #pragma unroll
  for (int mi = 0; mi < 8; ++mi) {
    #pragma unroll
    for (int r = 0; r < 4; ++r) {
      float s = 0.f;
      #pragma unroll
      for (int ni = 0; ni < 4; ++ni) {
        const float e = __expf(acc[mi][ni][r] * 0.125f);
        const __hip_bfloat16 h = __float2bfloat16(e);
        C[(size_t)(crow + mi * 16 + r) * ldc + ccol + ni * 16] = h;
        s += __bfloat162float(h);
      }
      #pragma unroll
      for (int mask = 1; mask < 16; mask <<= 1) s += __shfl_xor(s, mask);
      if (m16 == 0) atomicAdd(&Lrow[crow + mi * 16 + r], s);
    }
  }
}

// ---------------- PV gemm -> FINAL output: f32 * (1/l) + bias ---------------
__global__ __launch_bounds__(512) void gemm_pv_out(
    const __hip_bfloat16* __restrict__ A, int lda, long long sA,
    const __hip_bfloat16* __restrict__ B, int ldb, long long sB,
    float* __restrict__ Cv, int ldc, long long sC,
    const float* __restrict__ bias, const float* __restrict__ rsum, int K)
{
  const int bz = blockIdx.z;
  GEMM_CORE256(A + (size_t)bz * sA, lda, B + (size_t)bz * sB, ldb, K)
  float* C = Cv + (size_t)bz * sC;
  const float* rs = rsum + (size_t)bz * 2048;
  float bv[4];
  #pragma unroll
  for (int ni = 0; ni < 4; ++ni) bv[ni] = bias[ccol + ni * 16];
  #pragma unroll
  for (int mi = 0; mi < 8; ++mi) {
    float sc[4];
    #pragma unroll
    for (int r = 0; r < 4; ++r) sc[r] = 1.f / rs[crow + mi * 16 + r];
    #pragma unroll
    for (int ni = 0; ni < 4; ++ni)
      #pragma unroll
      for (int r = 0; r < 4; ++r)
        C[(size_t)(crow + mi * 16 + r) * ldc + ccol + ni * 16] =
            acc[mi][ni][r] * sc[r] + bv[ni];
  }
}

// ---------------------------------------------------------------------------
extern "C" void kernel_launch(void* const* d_in, const int* in_sizes, int n_in,
                              void* d_out, int out_size, void* d_ws, size_t ws_size,
                              hipStream_t stream) {
  const float* x     = (const float*)d_in[0];   // [8, 2048, 1024]
  const float* w_qkv = (const float*)d_in[1];   // [3072, 1024]
  const float* w_out = (const float*)d_in[2];   // [1024, 1024]
  const float* b_out = (const float*)d_in[3];   // [1024]
  float* out = (float*)d_out;

  constexpr int Bz = 8, N = 2048, D = 1024;
  constexpr int M = Bz * N;  // 16384
  constexpr size_t SLOT = (size_t)1024 * 1024;  // elems per 1024x1024 mat

  // ---- workspace ----
  // slots: 0 WkT | 1 Wob | 2 WqT | 3 WvT | 4 W~T | 5 Wc   (bf16, 12.6 MB)
  // then Xb [M,D] + Qx [M,D] + Vt [D,M] (bf16) + L [M] f32 + dyn P' (G*8.4MB)
  __hip_bfloat16* wsb = (__hip_bfloat16*)d_ws;
  __hip_bfloat16* WkT = wsb;
  __hip_bfloat16* WqT = wsb + 2 * SLOT;
  __hip_bfloat16* Wob = wsb + 1 * SLOT;
  __hip_bfloat16* Wt  = wsb + 4 * SLOT;
  char* p = (char*)(wsb + 6 * SLOT);
  __hip_bfloat16* Xb = (__hip_bfloat16*)p; p += (size_t)M * D * 2;
  __hip_bfloat16* Qx = (__hip_bfloat16*)p; p += (size_t)M * D * 2;
  __hip_bfloat16* Vt = (__hip_bfloat16*)p; p += (size_t)M * D * 2;
  float*          L  = (float*)p;          p += (size_t)M * 4;
  char* dyn = p;
  const size_t fixed_sz = (size_t)(dyn - (char*)d_ws);

  int G = 1;
  for (int g = 8; g >= 1; g >>= 1) {
    size_t dyn_sz = (size_t)g * N * N * 2;  // P' bf16
    if (fixed_sz + dyn_sz <= ws_size) { G = g; break; }
  }
  __hip_bfloat16* P = (__hip_bfloat16*)dyn;

  // phase 0: ONE prep kernel (cast x, cast w_out, transpose-cast w_qkv, zero L)
  prep<<<9488, 256, 0, stream>>>(x, w_qkv, w_out, Xb, wsb, Wob, L);
  // z=0: W~T = WkT @ WqT^T ; z=1: Wc = Wob @ WvT^T   (slot-stride batching)
  gemm_small<<<dim3(8, 8, 2), 256, 0, stream>>>(
      WkT, D, (long long)SLOT, WqT, D, (long long)SLOT, Wt, D, (long long)SLOT, D);

  // phase 1: Qx = Xb @ W~ ; Vt = (Xb @ Wc^T)^T  (B = [W~T ; Wc], 2048 rows)
  gemm_qv<<<dim3(8, M / 256), 512, 0, stream>>>(Xb, D, Wt, D, Qx, Vt, M, D);

  // phases 2-3: batched attention, groups of G
  for (int g = 0; g < Bz / G; ++g) {
    const size_t goff = (size_t)g * G * N;
    // P' = exp(Qx @ Xb^T * 0.125) (bf16) + atomic row sums into L
    gemm_qk_exp<<<dim3(N / 256, N / 256, G), 512, 0, stream>>>(
        Qx + goff * D, D, (long long)N * D,
        Xb + goff * D, D, (long long)N * D,
        P, N, (long long)N * N,
        L + goff, N, D);
    // y = (P' @ Vt^T)/l + b  -> final f32 output
    gemm_pv_out<<<dim3(D / 256, N / 256, G), 512, 0, stream>>>(
        P, N, (long long)N * N,
        Vt + goff, M, (long long)N,
        out + goff * D, D, (long long)N * D,
        b_out, L + goff, N);
  }
}